// Round 6
// baseline (1442.239 us; speedup 1.0000x reference)
//
#include <hip/hip_runtime.h>

// GCNConv: out = D^-1/2 (A+I) D^-1/2 X W + b
// N=100000, E=1600000, Din=Dout=128; x/W/b fp32, edge_index int32, out fp32.
//
// R5: LDS-accumulator aggregation. Edges coarse-sorted into 64-node buckets
//     (bucket = col>>6); one block per bucket accumulates sum(a*h[row]) into
//     float accum[64][128] in LDS via ds_add_f32 (no per-node CSR, no k_fine,
//     no dependent gather chain). h stored "split": word l of row n packs
//     bf16 cols (l, l+64) -> conflict-free LDS atomic addresses.
//   k_hist    : per-chunk LDS histogram -> histT[chunk][bucket] (coalesced)
//   k_colsum  : column exscan over chunks + per-bucket totals
//   k_scansmall: exscan totals -> totx (bucket starts)
//   k_place   : scatter ((c&63)<<17|row, w) via LDS cursors (no global atomics)
//   k_deg     : per-bucket LDS degree sum -> dis = rsqrt(1+sum w)
//   k_wprep/k_gemm: h = x@W bf16 MFMA, split-pair layout
//   k_agg     : per-bucket LDS accumulate + epilogue out = b + dn*(dn*h + acc)

#define CHUNK 4096   // edges per hist/place block

typedef __attribute__((ext_vector_type(8))) short short8;
typedef __attribute__((ext_vector_type(4))) float f32x4;

__device__ inline unsigned short f2bf(float f) {  // fp32 -> bf16 RNE
    unsigned u = __float_as_uint(f);
    u += 0x7fffu + ((u >> 16) & 1u);
    return (unsigned short)(u >> 16);
}
__device__ inline float bf_lo(unsigned u) { return __uint_as_float(u << 16); }
__device__ inline float bf_hi(unsigned u) { return __uint_as_float(u & 0xffff0000u); }

// ---- coarse histogram (bucket = col>>6), transposed coalesced output ----
__global__ __launch_bounds__(256) void k_hist(const int* __restrict__ col,
                                              int* __restrict__ histT,
                                              int E, int NC, int NCp) {
    __shared__ int lh[2048];
    int t = threadIdx.x, blk = blockIdx.x;
    for (int i = t; i < NC; i += 256) lh[i] = 0;
    __syncthreads();
    int base = blk * CHUNK;
    #pragma unroll
    for (int i = 0; i < CHUNK / 256; ++i) {
        int e = base + i * 256 + t;
        if (e < E) atomicAdd(&lh[col[e] >> 6], 1);
    }
    __syncthreads();
    for (int b = t; b < NC; b += 256) histT[blk * NCp + b] = lh[b];
}

// ---- column exclusive scan across chunks; tot[b] = bucket total ----
__global__ void k_colsum(int* __restrict__ histT, int* __restrict__ tot,
                         int NC, int NCp, int NBLK) {
    int b = blockIdx.x * blockDim.x + threadIdx.x;
    if (b >= NC) return;
    int run = 0;
    for (int blk = 0; blk < NBLK; ++blk) {
        int v = histT[blk * NCp + b];
        histT[blk * NCp + b] = run;
        run += v;
    }
    tot[b] = run;
}

__device__ inline int wave_incl_scan(int x, int lane) {
    #pragma unroll
    for (int d = 1; d < 64; d <<= 1) {
        int y = __shfl_up(x, d, 64);
        if (lane >= d) x += y;
    }
    return x;
}

// ---- single-block exclusive scan of tot[NC] -> totx[NC+1] (NC <= 2048) ----
__global__ void k_scansmall(const int* __restrict__ in, int* __restrict__ out, int M) {
    __shared__ int wsum[4];
    __shared__ int woff[4];
    int t = threadIdx.x, lane = t & 63, wid = t >> 6;
    int base = t * 8;
    int v[8];
    #pragma unroll
    for (int i = 0; i < 8; ++i) v[i] = (base + i < M) ? in[base + i] : 0;
    int run = 0;
    #pragma unroll
    for (int i = 0; i < 8; ++i) { int x = v[i]; v[i] = run; run += x; }
    int incl = wave_incl_scan(run, lane);
    int excl = incl - run;
    if (lane == 63) wsum[wid] = incl;
    __syncthreads();
    if (t == 0) {
        int r = 0;
        #pragma unroll
        for (int w = 0; w < 4; ++w) { int s = wsum[w]; woff[w] = r; r += s; }
        out[M] = r;   // total = E
    }
    __syncthreads();
    int off = woff[wid] + excl;
    #pragma unroll
    for (int i = 0; i < 8; ++i)
        if (base + i < M) out[base + i] = v[i] + off;
}

// ---- coarse placement via LDS cursors; payload ((c&63)<<17 | row, w) ----
__global__ __launch_bounds__(256) void k_place(const int* __restrict__ row,
                                               const int* __restrict__ col,
                                               const float* __restrict__ wgt,
                                               const int* __restrict__ histT,
                                               const int* __restrict__ totx,
                                               int2* __restrict__ srw,
                                               int E, int NC, int NCp) {
    __shared__ int lo[2048];
    int t = threadIdx.x, blk = blockIdx.x;
    for (int b = t; b < NC; b += 256) lo[b] = totx[b] + histT[blk * NCp + b];
    __syncthreads();
    int base = blk * CHUNK;
    #pragma unroll
    for (int i = 0; i < CHUNK / 256; ++i) {
        int e = base + i * 256 + t;
        if (e < E) {
            int c = col[e];
            int pos = atomicAdd(&lo[c >> 6], 1);
            srw[pos] = make_int2(((c & 63) << 17) | row[e], __float_as_int(wgt[e]));
        }
    }
}

// ---- per-bucket degree sum -> dis = rsqrt(1 + sum w) ----
__global__ __launch_bounds__(256) void k_deg(const int* __restrict__ totx,
                                             const int2* __restrict__ srw,
                                             float* __restrict__ dis, int N) {
    __shared__ float degf[64];
    int t = threadIdx.x, b = blockIdx.x;
    int nb = b << 6;
    int start = totx[b], end = totx[b + 1];
    if (t < 64) degf[t] = 1.0f;   // self-loop weight
    __syncthreads();
    for (int j = start + t; j < end; j += 256) {
        int2 s = srw[j];
        atomicAdd(&degf[s.x >> 17], __int_as_float(s.y));
    }
    __syncthreads();
    if (t < 64) {
        int n = nb + t;
        if (n < N) dis[n] = rsqrtf(degf[t]);
    }
}

// ---- W transpose + bf16 convert ----
__global__ void k_wprep(const float* __restrict__ W, unsigned short* __restrict__ Wtg) {
    int n = blockIdx.x;
    int k = threadIdx.x;
    Wtg[n * 128 + k] = f2bf(W[k * 128 + n]);
}

// ---- h = x @ W, bf16 MFMA. Output split layout: word l of row n = (col l, col l+64) ----
__global__ __launch_bounds__(256) void k_gemm(const float* __restrict__ x,
                                              const unsigned short* __restrict__ Wtg,
                                              unsigned int* __restrict__ hw, int N) {
    __shared__ short Xs[64][136];
    __shared__ short Ws[128][136];
    int t = threadIdx.x;
    int lane = t & 63, wid = t >> 6;
    int row0 = blockIdx.x * 64;
    {
        int r = t >> 2;
        int kseg = (t & 3) * 32;
        int gr = row0 + r;
        const float4* src = (const float4*)(x + (size_t)gr * 128 + kseg);
        #pragma unroll
        for (int i = 0; i < 4; ++i) {
            float4 v0 = make_float4(0.f, 0.f, 0.f, 0.f), v1 = v0;
            if (gr < N) { v0 = src[2 * i]; v1 = src[2 * i + 1]; }
            short8 p;
            p[0] = (short)f2bf(v0.x); p[1] = (short)f2bf(v0.y);
            p[2] = (short)f2bf(v0.z); p[3] = (short)f2bf(v0.w);
            p[4] = (short)f2bf(v1.x); p[5] = (short)f2bf(v1.y);
            p[6] = (short)f2bf(v1.z); p[7] = (short)f2bf(v1.w);
            *(short8*)&Xs[r][kseg + 8 * i] = p;
        }
    }
    {
        int n = t >> 1;
        int seg = (t & 1) * 64;
        const short* wsrc = (const short*)Wtg + n * 128 + seg;
        #pragma unroll
        for (int i = 0; i < 8; ++i)
            *(short8*)&Ws[n][seg + 8 * i] = *(const short8*)(wsrc + 8 * i);
    }
    __syncthreads();

    int q = lane >> 4;
    int m = lane & 15;
    f32x4 acc[8];
    #pragma unroll
    for (int tde = 0; tde < 8; ++tde) acc[tde] = (f32x4){0.f, 0.f, 0.f, 0.f};
    #pragma unroll
    for (int kc = 0; kc < 128; kc += 32) {
        short8 af = *(const short8*)&Xs[wid * 16 + m][kc + q * 8];
        #pragma unroll
        for (int tde = 0; tde < 8; ++tde) {
            short8 bf = *(const short8*)&Ws[tde * 16 + m][kc + q * 8];
            acc[tde] = __builtin_amdgcn_mfma_f32_16x16x32_bf16(af, bf, acc[tde], 0, 0, 0);
        }
    }
    // store split pairs: word (tde*16+m) = col tde*16+m (lo) | col tde*16+m+64 (hi)
    #pragma unroll
    for (int r = 0; r < 4; ++r) {
        int grow = row0 + wid * 16 + q * 4 + r;
        if (grow < N) {
            #pragma unroll
            for (int tde = 0; tde < 4; ++tde) {
                unsigned lo = f2bf(acc[tde][r]);
                unsigned hi = f2bf(acc[tde + 4][r]);
                hw[(size_t)grow * 64 + tde * 16 + m] = lo | (hi << 16);
            }
        }
    }
}

// ---- aggregation: 1 block per 64-node bucket, LDS accum[64][128] ----
__global__ __launch_bounds__(512) void k_agg(const unsigned int* __restrict__ hb,
                                             const float* __restrict__ dis,
                                             const int* __restrict__ totx,
                                             const int2* __restrict__ srw,
                                             const float* __restrict__ bias,
                                             float* __restrict__ out, int N) {
    __shared__ float accum[64 * 128];   // 32 KB; [c][l]=col l, [c][64+l]=col l+64
    int t = threadIdx.x;
    int lane = t & 63;
    int wid = __builtin_amdgcn_readfirstlane(t >> 6);   // 8 waves
    int b = blockIdx.x;
    int nb = b << 6;
    int start = totx[b], end = totx[b + 1];

    for (int i = t; i < 64 * 128; i += 512) accum[i] = 0.0f;
    __syncthreads();

    int j = start + wid * 4;
    while (j + 4 <= end) {
        int2 s0 = srw[j], s1 = srw[j + 1], s2 = srw[j + 2], s3 = srw[j + 3];
        int r0 = s0.x & 0x1FFFF, c0 = s0.x >> 17;
        int r1 = s1.x & 0x1FFFF, c1 = s1.x >> 17;
        int r2 = s2.x & 0x1FFFF, c2 = s2.x >> 17;
        int r3 = s3.x & 0x1FFFF, c3 = s3.x >> 17;
        unsigned u0 = hb[(size_t)r0 * 64 + lane];
        unsigned u1 = hb[(size_t)r1 * 64 + lane];
        unsigned u2 = hb[(size_t)r2 * 64 + lane];
        unsigned u3 = hb[(size_t)r3 * 64 + lane];
        float a0 = dis[r0] * __int_as_float(s0.y);
        float a1 = dis[r1] * __int_as_float(s1.y);
        float a2 = dis[r2] * __int_as_float(s2.y);
        float a3 = dis[r3] * __int_as_float(s3.y);
        atomicAdd(&accum[c0 * 128 + lane],      a0 * bf_lo(u0));
        atomicAdd(&accum[c0 * 128 + 64 + lane], a0 * bf_hi(u0));
        atomicAdd(&accum[c1 * 128 + lane],      a1 * bf_lo(u1));
        atomicAdd(&accum[c1 * 128 + 64 + lane], a1 * bf_hi(u1));
        atomicAdd(&accum[c2 * 128 + lane],      a2 * bf_lo(u2));
        atomicAdd(&accum[c2 * 128 + 64 + lane], a2 * bf_hi(u2));
        atomicAdd(&accum[c3 * 128 + lane],      a3 * bf_lo(u3));
        atomicAdd(&accum[c3 * 128 + 64 + lane], a3 * bf_hi(u3));
        j += 32;   // 8 waves * 4 edges
    }
    for (int e = j; e < end && e < j + 4; ++e) {   // tail
        int2 s = srw[e];
        int r = s.x & 0x1FFFF, c = s.x >> 17;
        unsigned u = hb[(size_t)r * 64 + lane];
        float a = dis[r] * __int_as_float(s.y);
        atomicAdd(&accum[c * 128 + lane],      a * bf_lo(u));
        atomicAdd(&accum[c * 128 + 64 + lane], a * bf_hi(u));
    }
    __syncthreads();

    // epilogue: out = b + dn*(dn*h[n] + accum)
    float bv0 = bias[lane], bv1 = bias[64 + lane];
    #pragma unroll
    for (int kk = 0; kk < 8; ++kk) {
        int c = wid + kk * 8;
        int n = nb + c;
        if (n < N) {
            float dn = dis[n];
            unsigned u = hb[(size_t)n * 64 + lane];
            float v0 = bv0 + dn * (dn * bf_lo(u) + accum[c * 128 + lane]);
            float v1 = bv1 + dn * (dn * bf_hi(u) + accum[c * 128 + 64 + lane]);
            out[(size_t)n * 128 + lane] = v0;
            out[(size_t)n * 128 + 64 + lane] = v1;
        }
    }
}

extern "C" void kernel_launch(void* const* d_in, const int* in_sizes, int n_in,
                              void* d_out, int out_size, void* d_ws, size_t ws_size,
                              hipStream_t stream) {
    const float* x     = (const float*)d_in[0];
    const int*   eidx  = (const int*)d_in[1];   // [2,E] int32
    const float* eattr = (const float*)d_in[2];
    const float* W     = (const float*)d_in[3];
    const float* bias  = (const float*)d_in[4];
    int N = in_sizes[0] / 128;
    int E = in_sizes[2];
    const int* row = eidx;
    const int* col = eidx + E;

    int NC = (N + 63) >> 6;                    // 1563 buckets of 64 nodes
    int NCp = (NC + 7) & ~7;                   // padded stride
    int NBLK = (E + CHUNK - 1) / CHUNK;        // 391 hist/place chunks

    char* p = (char*)d_ws;
    auto carve = [&](size_t bytes) {
        char* q = p;
        p += (bytes + 255) & ~(size_t)255;
        return q;
    };
    unsigned int* hw     = (unsigned int*)carve((size_t)N * 64 * sizeof(unsigned int));
    unsigned short* Wtg  = (unsigned short*)carve(128 * 128 * sizeof(unsigned short));
    float* dis    = (float*)carve((size_t)N * sizeof(float));
    int*   histT  = (int*)carve((size_t)NBLK * NCp * sizeof(int));
    int*   tot    = (int*)carve((size_t)NC * sizeof(int));
    int*   totx   = (int*)carve((size_t)(NC + 1) * sizeof(int));
    int2*  srw    = (int2*)carve((size_t)E * sizeof(int2));

    k_hist<<<NBLK, 256, 0, stream>>>(col, histT, E, NC, NCp);
    k_colsum<<<(NC + 255) / 256, 256, 0, stream>>>(histT, tot, NC, NCp, NBLK);
    k_scansmall<<<1, 256, 0, stream>>>(tot, totx, NC);
    k_place<<<NBLK, 256, 0, stream>>>(row, col, eattr, histT, totx, srw, E, NC, NCp);
    k_deg<<<NC, 256, 0, stream>>>(totx, srw, dis, N);
    k_wprep<<<128, 128, 0, stream>>>(W, Wtg);
    k_gemm<<<(N + 63) / 64, 256, 0, stream>>>(x, Wtg, hw, N);
    k_agg<<<NC, 512, 0, stream>>>(hw, dis, totx, srw, bias, (float*)d_out, N);
}

// Round 7
// 278.036 us; speedup vs baseline: 5.1872x; 5.1872x over previous
//
#include <hip/hip_runtime.h>

// GCNConv: out = D^-1/2 (A+I) D^-1/2 X W + b
// N=100000, E=1600000, Din=Dout=128; x/W/b fp32, edge_index int32, out fp32.
//
// R6: R4 structure (two-level counting sort, zero global atomics) +
//  - gather v4: cooperative 16-edge payload fetch (lanes 0..15, one dwordx2)
//    + v_readlane broadcast; 16 independent h-row loads in flight; uniform
//    tail guards. Kills the 2 broadcast-redundant vmem ops per edge.
//  - k_fine weighted degree in FIXED-POINT INT LDS atomics (w * 2^18).
//    gfx950 LDS *float* atomicAdd serializes per-lane (~256cyc/wave-op,
//    measured R5 k_agg 469 cyc/edge) -- never bulk ds_add_f32.

#define ELEMS_PER_SCAN_BLOCK 2048  // 256 threads * 8
#define CHUNK 4096                 // edges per hist/place block
#define WSCALE 262144.0f           // 2^18 fixed-point degree scale
#define WSCALE_INV (1.0f / 262144.0f)

typedef __attribute__((ext_vector_type(8))) short short8;
typedef __attribute__((ext_vector_type(4))) float f32x4;

__device__ inline unsigned short f2bf(float f) {  // fp32 -> bf16 RNE
    unsigned u = __float_as_uint(f);
    u += 0x7fffu + ((u >> 16) & 1u);
    return (unsigned short)(u >> 16);
}
__device__ inline float bf_lo(unsigned u) { return __uint_as_float(u << 16); }
__device__ inline float bf_hi(unsigned u) { return __uint_as_float(u & 0xffff0000u); }

// ---- coarse histogram: LDS only ----
__global__ __launch_bounds__(256) void k_hist(const int* __restrict__ col,
                                              int* __restrict__ histg,
                                              int E, int NC, int NBLK) {
    __shared__ int lh[1024];
    int t = threadIdx.x, blk = blockIdx.x;
    for (int i = t; i < 1024; i += 256) lh[i] = 0;
    __syncthreads();
    int base = blk * CHUNK;
    #pragma unroll
    for (int i = 0; i < CHUNK / 256; ++i) {
        int e = base + i * 256 + t;
        if (e < E) atomicAdd(&lh[col[e] >> 7], 1);
    }
    __syncthreads();
    for (int b = t; b < NC; b += 256) histg[b * NBLK + blk] = lh[b];
}

// ---- scan (3 kernels) ----
__device__ inline int wave_incl_scan(int x, int lane) {
    #pragma unroll
    for (int d = 1; d < 64; d <<= 1) {
        int y = __shfl_up(x, d, 64);
        if (lane >= d) x += y;
    }
    return x;
}

__global__ void k_scan1(const int* __restrict__ in, int* __restrict__ out,
                        int* __restrict__ bsum, int M) {
    __shared__ int wsum[4];
    __shared__ int woff[4];
    int t = threadIdx.x, lane = t & 63, wid = t >> 6;
    int base = blockIdx.x * ELEMS_PER_SCAN_BLOCK + t * 8;
    int v[8];
    #pragma unroll
    for (int i = 0; i < 8; ++i) v[i] = (base + i < M) ? in[base + i] : 0;
    int run = 0;
    #pragma unroll
    for (int i = 0; i < 8; ++i) { int x = v[i]; v[i] = run; run += x; }
    int incl = wave_incl_scan(run, lane);
    int excl = incl - run;
    if (lane == 63) wsum[wid] = incl;
    __syncthreads();
    if (t == 0) {
        int r = 0;
        #pragma unroll
        for (int w = 0; w < 4; ++w) { int s = wsum[w]; woff[w] = r; r += s; }
        bsum[blockIdx.x] = r;
    }
    __syncthreads();
    int off = woff[wid] + excl;
    #pragma unroll
    for (int i = 0; i < 8; ++i)
        if (base + i < M) out[base + i] = v[i] + off;
}

__global__ void k_scan2(const int* __restrict__ bsum, int* __restrict__ boff, int NB) {
    __shared__ int wsum[4];
    __shared__ int woff[4];
    int t = threadIdx.x, lane = t & 63, wid = t >> 6;
    int x = (t < NB) ? bsum[t] : 0;
    int incl = wave_incl_scan(x, lane);
    int excl = incl - x;
    if (lane == 63) wsum[wid] = incl;
    __syncthreads();
    if (t == 0) {
        int r = 0;
        #pragma unroll
        for (int w = 0; w < 4; ++w) { int s = wsum[w]; woff[w] = r; r += s; }
    }
    __syncthreads();
    if (t < NB) boff[t] = woff[wid] + excl;
}

__global__ void k_scan3(int* __restrict__ arr, const int* __restrict__ boff, int M) {
    int t = threadIdx.x;
    int base = blockIdx.x * ELEMS_PER_SCAN_BLOCK + t * 8;
    int off = boff[blockIdx.x];
    #pragma unroll
    for (int i = 0; i < 8; ++i) {
        int idx = base + i;
        if (idx < M) arr[idx] += off;
    }
}

// ---- coarse placement: LDS cursors; payload ((c&127)<<17|row, w) ----
__global__ __launch_bounds__(256) void k_place(const int* __restrict__ row,
                                               const int* __restrict__ col,
                                               const float* __restrict__ wgt,
                                               const int* __restrict__ histg,
                                               int2* __restrict__ srw,
                                               int E, int NC, int NBLK) {
    __shared__ int lo[1024];
    int t = threadIdx.x, blk = blockIdx.x;
    for (int b = t; b < NC; b += 256) lo[b] = histg[b * NBLK + blk];
    __syncthreads();
    int base = blk * CHUNK;
    #pragma unroll
    for (int i = 0; i < CHUNK / 256; ++i) {
        int e = base + i * 256 + t;
        if (e < E) {
            int c = col[e];
            int pos = atomicAdd(&lo[c >> 7], 1);
            srw[pos] = make_int2(((c & 127) << 17) | row[e], __float_as_int(wgt[e]));
        }
    }
}

// ---- fine pass: exact CSR within each 128-node bucket + dis + spack ----
__global__ __launch_bounds__(256) void k_fine(const int* __restrict__ histg,
                                              const int2* __restrict__ srw,
                                              int* __restrict__ rowptr,
                                              float* __restrict__ dis,
                                              int2* __restrict__ spack,
                                              int E, int N, int NC, int NBLK) {
    __shared__ int cnt128[128];
    __shared__ int degi[128];      // fixed-point (2^18) weighted degree
    __shared__ int cur128[128];
    __shared__ int wtot[2];
    int t = threadIdx.x, b = blockIdx.x;
    int nb = b << 7;
    int start = histg[b * NBLK];
    int end = (b == NC - 1) ? E : histg[(b + 1) * NBLK];
    if (t < 128) { cnt128[t] = 0; degi[t] = 0; }
    __syncthreads();
    // phase 1: histogram + fixed-point weighted degree (int LDS atomics only)
    for (int j = start + t; j < end; j += 256) {
        int2 s = srw[j];
        int c = s.x >> 17;
        atomicAdd(&cnt128[c], 1);
        atomicAdd(&degi[c], (int)(__int_as_float(s.y) * WSCALE + 0.5f));
    }
    __syncthreads();
    // phase 2: 128-entry exclusive scan, write rowptr/dis, seed cursors
    int v = 0, incl = 0;
    if (t < 128) {
        v = cnt128[t];
        incl = wave_incl_scan(v, t & 63);
        if ((t & 63) == 63) wtot[t >> 6] = incl;
    }
    __syncthreads();
    if (t < 128) {
        int excl = incl - v + ((t >= 64) ? wtot[0] : 0);
        int p = start + excl;
        cur128[t] = p;
        int n = nb + t;
        if (n < N) {
            rowptr[n] = p;
            dis[n] = rsqrtf(1.0f + (float)degi[t] * WSCALE_INV);  // 1.0 = self loop
        }
    }
    if (t == 0 && b == NC - 1) rowptr[N] = E;
    __syncthreads();
    // phase 3: final placement (strip c bits -> (row, w))
    for (int j = start + t; j < end; j += 256) {
        int2 s = srw[j];
        int c = s.x >> 17;
        int pos = atomicAdd(&cur128[c], 1);
        spack[pos] = make_int2(s.x & 0x1FFFF, s.y);
    }
}

// ---- W transpose + bf16 convert ----
__global__ void k_wprep(const float* __restrict__ W, unsigned short* __restrict__ Wtg) {
    int n = blockIdx.x;
    int k = threadIdx.x;
    Wtg[n * 128 + k] = f2bf(W[k * 128 + n]);
}

// ---- h = x @ W, bf16 MFMA 16x16x32. 64 rows x 128 cols / block, 4 waves. ----
__global__ __launch_bounds__(256) void k_gemm(const float* __restrict__ x,
                                              const unsigned short* __restrict__ Wtg,
                                              unsigned short* __restrict__ h, int N) {
    __shared__ short Xs[64][136];
    __shared__ short Ws[128][136];
    int t = threadIdx.x;
    int lane = t & 63, wid = t >> 6;
    int row0 = blockIdx.x * 64;
    {
        int r = t >> 2;
        int kseg = (t & 3) * 32;
        int gr = row0 + r;
        const float4* src = (const float4*)(x + (size_t)gr * 128 + kseg);
        #pragma unroll
        for (int i = 0; i < 4; ++i) {
            float4 v0 = make_float4(0.f, 0.f, 0.f, 0.f), v1 = v0;
            if (gr < N) { v0 = src[2 * i]; v1 = src[2 * i + 1]; }
            short8 p;
            p[0] = (short)f2bf(v0.x); p[1] = (short)f2bf(v0.y);
            p[2] = (short)f2bf(v0.z); p[3] = (short)f2bf(v0.w);
            p[4] = (short)f2bf(v1.x); p[5] = (short)f2bf(v1.y);
            p[6] = (short)f2bf(v1.z); p[7] = (short)f2bf(v1.w);
            *(short8*)&Xs[r][kseg + 8 * i] = p;
        }
    }
    {
        int n = t >> 1;
        int seg = (t & 1) * 64;
        const short* wsrc = (const short*)Wtg + n * 128 + seg;
        #pragma unroll
        for (int i = 0; i < 8; ++i)
            *(short8*)&Ws[n][seg + 8 * i] = *(const short8*)(wsrc + 8 * i);
    }
    __syncthreads();

    int q = lane >> 4;
    int m = lane & 15;
    f32x4 acc[8];
    #pragma unroll
    for (int tde = 0; tde < 8; ++tde) acc[tde] = (f32x4){0.f, 0.f, 0.f, 0.f};
    #pragma unroll
    for (int kc = 0; kc < 128; kc += 32) {
        short8 af = *(const short8*)&Xs[wid * 16 + m][kc + q * 8];
        #pragma unroll
        for (int tde = 0; tde < 8; ++tde) {
            short8 bf = *(const short8*)&Ws[tde * 16 + m][kc + q * 8];
            acc[tde] = __builtin_amdgcn_mfma_f32_16x16x32_bf16(af, bf, acc[tde], 0, 0, 0);
        }
    }
    #pragma unroll
    for (int r = 0; r < 4; ++r) {
        int grow = row0 + wid * 16 + q * 4 + r;
        if (grow < N) {
            #pragma unroll
            for (int tde = 0; tde < 8; ++tde)
                h[(size_t)grow * 128 + tde * 16 + m] = f2bf(acc[tde][r]);
        }
    }
}

// ---- gather v4: 1 wave/node; cooperative 16-edge payload fetch +
//      readlane broadcast; 16 independent row loads in flight ----
__global__ __launch_bounds__(256) void k_gather(const unsigned int* __restrict__ hb,
                                                const float* __restrict__ dis,
                                                const int* __restrict__ rowptr,
                                                const long* __restrict__ spackl,
                                                const float* __restrict__ bias,
                                                float* __restrict__ out, int N) {
    int gid = blockIdx.x * blockDim.x + threadIdx.x;
    int node = gid >> 6;
    int lane = gid & 63;
    if (node >= N) return;
    node = __builtin_amdgcn_readfirstlane(node);

    float dn = dis[node];
    unsigned u = hb[(size_t)node * 64 + lane];
    float accx = dn * bf_lo(u);
    float accy = dn * bf_hi(u);

    int jb = rowptr[node], je = rowptr[node + 1];

    for (int j = jb; j < je; j += 16) {
        // lanes 0..15: fetch 16 edge payloads (one coalesced 128B dwordx2)
        int idx = j + lane;
        long q = 0;
        if (lane < 16 && idx < je) q = __builtin_nontemporal_load(spackl + idx);
        int rsrc = (int)q;                                   // row (17 bits)
        float dsrc = (lane < 16) ? dis[rsrc] : 0.0f;         // 16-lane gather
        float aval = dsrc * __uint_as_float((unsigned)((unsigned long)q >> 32));
        int rem = je - j;
        if (rem >= 16) {
            #pragma unroll
            for (int e = 0; e < 16; ++e) {
                int r = __builtin_amdgcn_readlane(rsrc, e);
                float a = __uint_as_float(__builtin_amdgcn_readlane(__float_as_uint(aval), e));
                unsigned uu = hb[(size_t)r * 64 + lane];
                accx = fmaf(a, bf_lo(uu), accx);
                accy = fmaf(a, bf_hi(uu), accy);
            }
        } else {
            #pragma unroll
            for (int e = 0; e < 16; ++e) {
                if (e < rem) {   // wave-uniform branch: skips row load entirely
                    int r = __builtin_amdgcn_readlane(rsrc, e);
                    float a = __uint_as_float(__builtin_amdgcn_readlane(__float_as_uint(aval), e));
                    unsigned uu = hb[(size_t)r * 64 + lane];
                    accx = fmaf(a, bf_lo(uu), accx);
                    accy = fmaf(a, bf_hi(uu), accy);
                }
            }
        }
    }

    int c0 = lane * 2;
    float2 bv = *(const float2*)(bias + c0);
    float2 o;
    o.x = bv.x + dn * accx;
    o.y = bv.y + dn * accy;
    union { float2 f; double d; } cvt;
    cvt.f = o;
    __builtin_nontemporal_store(cvt.d, (double*)(out + (size_t)node * 128 + c0));
}

extern "C" void kernel_launch(void* const* d_in, const int* in_sizes, int n_in,
                              void* d_out, int out_size, void* d_ws, size_t ws_size,
                              hipStream_t stream) {
    const float* x     = (const float*)d_in[0];
    const int*   eidx  = (const int*)d_in[1];   // [2,E] int32
    const float* eattr = (const float*)d_in[2];
    const float* W     = (const float*)d_in[3];
    const float* bias  = (const float*)d_in[4];
    int N = in_sizes[0] / 128;
    int E = in_sizes[2];
    const int* row = eidx;
    const int* col = eidx + E;

    int NC = (N + 127) >> 7;                       // 782 coarse buckets
    int NBLK = (E + CHUNK - 1) / CHUNK;            // 391 hist/place blocks

    char* p = (char*)d_ws;
    auto carve = [&](size_t bytes) {
        char* q = p;
        p += (bytes + 255) & ~(size_t)255;
        return q;
    };
    unsigned short* h   = (unsigned short*)carve((size_t)N * 128 * sizeof(unsigned short));
    unsigned short* Wtg = (unsigned short*)carve(128 * 128 * sizeof(unsigned short));
    float* dis    = (float*)carve((size_t)N * sizeof(float));
    int*   rowptr = (int*)carve((size_t)(N + 1) * sizeof(int));
    int*   histg  = (int*)carve((size_t)NC * NBLK * sizeof(int));
    int2*  srw    = (int2*)carve((size_t)E * sizeof(int2));
    int2*  spack  = (int2*)carve((size_t)E * sizeof(int2));
    int*   bsum   = (int*)carve(256 * sizeof(int));
    int*   boff   = (int*)carve(256 * sizeof(int));

    int M = NC * NBLK;
    int NBs = (M + ELEMS_PER_SCAN_BLOCK - 1) / ELEMS_PER_SCAN_BLOCK;

    k_hist<<<NBLK, 256, 0, stream>>>(col, histg, E, NC, NBLK);
    k_scan1<<<NBs, 256, 0, stream>>>(histg, histg, bsum, M);
    k_scan2<<<1, 256, 0, stream>>>(bsum, boff, NBs);
    k_scan3<<<NBs, 256, 0, stream>>>(histg, boff, M);
    k_place<<<NBLK, 256, 0, stream>>>(row, col, eattr, histg, srw, E, NC, NBLK);
    k_fine<<<NC, 256, 0, stream>>>(histg, srw, rowptr, dis, spack, E, N, NC, NBLK);
    k_wprep<<<128, 128, 0, stream>>>(W, Wtg);
    k_gemm<<<(N + 63) / 64, 256, 0, stream>>>(x, Wtg, h, N);
    {
        size_t threads = (size_t)N * 64;
        int blocks = (int)((threads + 255) / 256);
        k_gather<<<blocks, 256, 0, stream>>>((const unsigned int*)h, dis, rowptr,
                                             (const long*)spack, bias, (float*)d_out, N);
    }
}